// Round 18
// baseline (313.737 us; speedup 1.0000x reference)
//
#include <hip/hip_runtime.h>
#include <hip/hip_bf16.h>

// MoE PHM MLP, MI355X. B=2,S=2048,D=1024 -> T=4096 tokens; E=8, N=4, HID=4096.
// Launch chain (r15 best + this round: launch_bounds (256,3) on GEMMs for
// 3 blocks/CU residency -- LDS 48.5KB x3 = 145.5KB < 160KB, VGPR 108 < 170):
//   front_k : router (f64 logits/argmax, f32 softmax, bf16 x-copy, prob sums)
//   plan_k  : block 0 = histogram/stable-rank/offsets/aux; blocks 1..8192 =
//             W_fc materialization (overlaps plan)
//   mid_k   : fc GEMM (128x256, indirect A via tok[], leaky(0.5)^2 -> h bf16)
//             + W_proj materialization
//   proj_k  : proj GEMM (128x256, split-K=2) -> BF16 partials BY SLOT
//   reduce_k: out[tok[slot]] = f32(P0[slot]) + f32(P1[slot])
// GEMMs: m97 2-barrier single-buffer structure, XOR-swizzled LDS via
// pre-swizzled global source (measured 0 bank conflicts), XCD-aware decode.

#define T_TOK 4096
#define DIM   1024
#define NEXP  8
#define HIDD  4096
#define SLOTS 5120

static constexpr size_t OFF_WFC   = 0;
static constexpr size_t OFF_WPROJ = 67108864ull;
static constexpr size_t OFF_XB    = 134217728ull;
static constexpr size_t OFF_H     = 144703488ull;
static constexpr size_t OFF_BSUM  = 186646528ull;                     // 64 KB
static constexpr size_t OFF_EIDX  = OFF_BSUM + 1024*8*8;
static constexpr size_t OFF_TOK   = OFF_EIDX + (size_t)T_TOK*4;
static constexpr size_t OFF_CNT   = OFF_TOK + (size_t)SLOTS*4;

typedef __attribute__((ext_vector_type(8))) short short8;
typedef __attribute__((ext_vector_type(4))) float f32x4;

static __device__ __forceinline__ ushort f2bf(float f) {
    __hip_bfloat16 h = __float2bfloat16(f);
    return __builtin_bit_cast(ushort, h);
}

static __device__ __forceinline__ float bf2f(ushort u) {
    return __builtin_bit_cast(float, (unsigned)u << 16);
}

static __device__ __forceinline__ ushort4 f4bf(float4 v) {
    ushort4 b;
    b.x = f2bf(v.x); b.y = f2bf(v.y); b.z = f2bf(v.z); b.w = f2bf(v.w);
    return b;
}

static __device__ __forceinline__ void gload_lds16(const ushort* g, ushort* l) {
    __builtin_amdgcn_global_load_lds((const __attribute__((address_space(1))) void*)g,
                                     (__attribute__((address_space(3))) void*)l,
                                     16, 0, 0);
}

// ---- front: router (f64 logits, argmax, bf16 x copy, per-block prob sums) ---
__global__ __launch_bounds__(256) void front_k(const float* __restrict__ x,
                                               const float* __restrict__ wr,
                                               double* __restrict__ bsum,
                                               int* __restrict__ eidx,
                                               ushort* __restrict__ xb)
{
    __shared__ double shp[4][8];
    int tid = threadIdx.x;
    int w = tid >> 6, lane = tid & 63;
    int t = blockIdx.x * 4 + w;
    const float4* xr = (const float4*)(x + (size_t)t * DIM);
    float4 xv[4];
#pragma unroll
    for (int q = 0; q < 4; q++) xv[q] = xr[q * 64 + lane];
    ushort4* xo = (ushort4*)(xb + (size_t)t * DIM);
#pragma unroll
    for (int q = 0; q < 4; q++) xo[q * 64 + lane] = f4bf(xv[q]);
    double lg[8];
#pragma unroll
    for (int e = 0; e < 8; e++) {
        const float4* wv = (const float4*)(wr + (size_t)e * DIM);
        double s = 0.0;
#pragma unroll
        for (int q = 0; q < 4; q++) {
            float4 a = xv[q], b = wv[q * 64 + lane];
            s += (double)a.x * b.x + (double)a.y * b.y + (double)a.z * b.z + (double)a.w * b.w;
        }
#pragma unroll
        for (int d = 1; d < 64; d <<= 1) s += __shfl_xor(s, d);
        lg[e] = s;
    }
    double m = lg[0];
#pragma unroll
    for (int e = 1; e < 8; e++) m = lg[e] > m ? lg[e] : m;
    // softmax in f32 (argmax stays on f64 logits; probs only feed aux_loss)
    float ex[8], sum = 0.f;
#pragma unroll
    for (int e = 0; e < 8; e++) { ex[e] = __expf((float)(lg[e] - m)); sum += ex[e]; }
    if (lane < 8) shp[w][lane] = (double)(ex[lane] / sum);
    if (lane == 0) {
        int am = 0; double bv = lg[0];
#pragma unroll
        for (int e = 1; e < 8; e++) if (lg[e] > bv) { bv = lg[e]; am = e; }  // first-max = jnp.argmax
        eidx[t] = am;
    }
    __syncthreads();
    if (tid < 8)
        bsum[(size_t)blockIdx.x * 8 + tid] =
            shp[0][tid] + shp[1][tid] + shp[2][tid] + shp[3][tid];
}

// --- plan: block 0 = histogram/rank/offsets/aux; blocks 1.. = W_fc wmat -----
__global__ __launch_bounds__(256) void plan_k(const double* __restrict__ bsum,
                                              const int* __restrict__ eidx,
                                              int* __restrict__ counts,
                                              int* __restrict__ offsets,
                                              int* __restrict__ tok,
                                              float* __restrict__ auxout,
                                              const float* __restrict__ Afc,
                                              const float* __restrict__ Sfc,
                                              ushort* __restrict__ Wfc)
{
    __shared__ int hist[256][8];
    __shared__ double red[256][8];
    __shared__ int offs[8];
    __shared__ float Ash[64];
    int tid = threadIdx.x;
    if (blockIdx.x > 0) {
        // -- W_fc: W[e][j*1024+o][k*256+l] = sum_i A[i,j,k]S[i,o,l], ushort4 --
        int b2 = blockIdx.x - 1;
        int e = b2 >> 10, o = b2 & 1023;
        if (tid < 64) Ash[tid] = Afc[e * 64 + tid];
        __syncthreads();
        int k = tid >> 6, lq = tid & 63;           // k slice, l/4 index
        float4 sv[4];
#pragma unroll
        for (int i = 0; i < 4; i++)
            sv[i] = *(const float4*)&Sfc[((size_t)(e * 4 + i) * 1024 + o) * 256 + lq * 4];
        size_t base = (size_t)e * 4194304ull;
#pragma unroll
        for (int j = 0; j < 4; j++) {
            float a0 = Ash[j * 4 + k], a1 = Ash[16 + j * 4 + k];
            float a2 = Ash[32 + j * 4 + k], a3 = Ash[48 + j * 4 + k];
            float4 v;
            v.x = a0 * sv[0].x + a1 * sv[1].x + a2 * sv[2].x + a3 * sv[3].x;
            v.y = a0 * sv[0].y + a1 * sv[1].y + a2 * sv[2].y + a3 * sv[3].y;
            v.z = a0 * sv[0].z + a1 * sv[1].z + a2 * sv[2].z + a3 * sv[3].z;
            v.w = a0 * sv[0].w + a1 * sv[1].w + a2 * sv[2].w + a3 * sv[3].w;
            *(ushort4*)&Wfc[base + (size_t)(j * 1024 + o) * 1024 + k * 256 + lq * 4] = f4bf(v);
        }
        return;
    }
    // ------------------------------ plan (block 0) --------------------------
    for (int i = tid; i < SLOTS; i += 256) tok[i] = -1;
    int base = tid * 16;
    int le[16];
    int lc[8] = {0,0,0,0,0,0,0,0};
#pragma unroll
    for (int j = 0; j < 16; j++) { le[j] = eidx[base + j]; lc[le[j]]++; }
#pragma unroll
    for (int e = 0; e < 8; e++) hist[tid][e] = lc[e];
    __syncthreads();
    for (int s = 1; s < 256; s <<= 1) {
        int v[8];
        if (tid >= s) {
#pragma unroll
            for (int e = 0; e < 8; e++) v[e] = hist[tid - s][e];
        }
        __syncthreads();
        if (tid >= s) {
#pragma unroll
            for (int e = 0; e < 8; e++) hist[tid][e] += v[e];
        }
        __syncthreads();
    }
    int myBase[8];
#pragma unroll
    for (int e = 0; e < 8; e++) myBase[e] = hist[tid][e] - lc[e];
    if (tid == 0) {
        int off = 0;
#pragma unroll
        for (int e = 0; e < 8; e++) {
            int c = hist[255][e];
            counts[e] = c;
            offsets[e] = off; offs[e] = off;
            off += (c + 127) & ~127;
        }
    }
    __syncthreads();
    int cur[8];
#pragma unroll
    for (int e = 0; e < 8; e++) cur[e] = myBase[e];
#pragma unroll
    for (int j = 0; j < 16; j++) {
        int e = le[j];
        tok[offs[e] + cur[e]++] = base + j;
    }
    double ps[8] = {0, 0, 0, 0, 0, 0, 0, 0};
    for (int b = tid; b < 1024; b += 256) {
#pragma unroll
        for (int e = 0; e < 8; e++) ps[e] += bsum[(size_t)b * 8 + e];
    }
#pragma unroll
    for (int e = 0; e < 8; e++) red[tid][e] = ps[e];
    __syncthreads();
    for (int s = 128; s > 0; s >>= 1) {
        if (tid < s) {
#pragma unroll
            for (int e = 0; e < 8; e++) red[tid][e] += red[tid + s][e];
        }
        __syncthreads();
    }
    if (tid == 0) {
        double aux = 0.0;
#pragma unroll
        for (int e = 0; e < 8; e++)
            aux += ((double)hist[255][e] / T_TOK) * (red[0][e] / T_TOK);
        auxout[0] = (float)(aux * NEXP);
    }
}

// ---- mid: blocks [0,640) = fc GEMM, [640,2688) = W_proj materialization ----
__global__ __launch_bounds__(256, 3) void mid_k(const ushort* __restrict__ xb,
                                                const ushort* __restrict__ Wfc,
                                                ushort* __restrict__ h,
                                                const int* __restrict__ counts,
                                                const int* __restrict__ offsets,
                                                const int* __restrict__ tok,
                                                const float* __restrict__ Apj,
                                                const float* __restrict__ Spj,
                                                ushort* __restrict__ Wpj)
{
    __shared__ __align__(16) ushort As[128 * 64];
    __shared__ __align__(16) ushort Bs[256 * 64];
    __shared__ float Ashf[64];
    int b = blockIdx.x;
    int tid = threadIdx.x;
    if (b >= 640) {
        // W_proj: W[e][j*256+o][k*1024+l] = sum_i A[i,j,k]S[i,o,l], ushort4 ---
        int b2 = b - 640;
        int e = b2 >> 8, o = b2 & 255;
        if (tid < 64) Ashf[tid] = Apj[e * 64 + tid];
        __syncthreads();
        float4 sv[4];
#pragma unroll
        for (int i = 0; i < 4; i++)
            sv[i] = *(const float4*)&Spj[((size_t)(e * 4 + i) * 256 + o) * 1024 + tid * 4];
        size_t base = (size_t)e * 4194304ull;
#pragma unroll
        for (int j = 0; j < 4; j++)
#pragma unroll
            for (int k = 0; k < 4; k++) {
                float a0 = Ashf[j * 4 + k], a1 = Ashf[16 + j * 4 + k];
                float a2 = Ashf[32 + j * 4 + k], a3 = Ashf[48 + j * 4 + k];
                float4 v;
                v.x = a0 * sv[0].x + a1 * sv[1].x + a2 * sv[2].x + a3 * sv[3].x;
                v.y = a0 * sv[0].y + a1 * sv[1].y + a2 * sv[2].y + a3 * sv[3].y;
                v.z = a0 * sv[0].z + a1 * sv[1].z + a2 * sv[2].z + a3 * sv[3].z;
                v.w = a0 * sv[0].w + a1 * sv[1].w + a2 * sv[2].w + a3 * sv[3].w;
                *(ushort4*)&Wpj[base + (size_t)(j * 256 + o) * 4096 + k * 1024 + tid * 4] = f4bf(v);
            }
        return;
    }
    // ------------------------------ fc GEMM ---------------------------------
    constexpr int KDIM = 1024;
    constexpr int NDIM = 4096;
    int r = b >> 3;
    int nb = (b & 7) * 2 + r / 40;     // 16 n-panels, 2 per XCD
    int ms = r % 40;
    int e = -1, mt = 0, acct = 0;
#pragma unroll
    for (int i = 0; i < 8; i++) {
        int tiles = (counts[i] + 127) >> 7;
        if (e < 0 && ms < acct + tiles) { e = i; mt = ms - acct; }
        acct += tiles;
    }
    if (e < 0) return;
    int m_base = offsets[e] + mt * 128;
    int n_base = nb * 256;
    int w = tid >> 6, lane = tid & 63;
    int wm = w >> 1, wn = w & 1;
    const ushort* Bb = Wfc + (size_t)e * NDIM * KDIM + (size_t)n_base * KDIM;
    int lr = lane >> 3;                        // staging row within 8-row group
    int lcs = (((lane & 7) ^ lr) << 3);        // swizzled source chunk (ushorts)
    const ushort* arow[4];
#pragma unroll
    for (int i = 0; i < 4; i++) {
        int sl = m_base + i * 32 + w * 8 + lr;
        int rt = tok[sl]; if (rt < 0) rt = 0;
        arow[i] = xb + (size_t)rt * KDIM + lcs;
    }
    f32x4 acc[4][8];
#pragma unroll
    for (int i = 0; i < 4; i++)
#pragma unroll
        for (int j = 0; j < 8; j++) acc[i][j] = (f32x4){0.f, 0.f, 0.f, 0.f};

    for (int t = 0; t < KDIM / 64; t++) {
        int k0 = t * 64;
#pragma unroll
        for (int i = 0; i < 4; i++)
            gload_lds16(arow[i] + k0, &As[(i * 32 + w * 8) * 64]);
#pragma unroll
        for (int i = 0; i < 8; i++) {
            int r0 = i * 32 + w * 8;
            gload_lds16(Bb + (size_t)(r0 + lr) * KDIM + k0 + lcs, &Bs[r0 * 64]);
        }
        __syncthreads();
#pragma unroll
        for (int ks = 0; ks < 2; ks++) {
            short8 a[4], bfr[8];
            int ca = (((ks * 4 + (lane >> 4)) ^ (lane & 7)) << 3);
#pragma unroll
            for (int f = 0; f < 4; f++)
                a[f] = *(const short8*)&As[(wm * 64 + f * 16 + (lane & 15)) * 64 + ca];
#pragma unroll
            for (int f = 0; f < 8; f++)
                bfr[f] = *(const short8*)&Bs[(wn * 128 + f * 16 + (lane & 15)) * 64 + ca];
#pragma unroll
            for (int mf = 0; mf < 4; mf++)
#pragma unroll
                for (int nf = 0; nf < 8; nf++)
                    acc[mf][nf] = __builtin_amdgcn_mfma_f32_16x16x32_bf16(a[mf], bfr[nf], acc[mf][nf], 0, 0, 0);
        }
        __syncthreads();
    }

    int col0 = n_base + wn * 128;
    int row0 = wm * 64 + (lane >> 4) * 4;   // C/D: col=lane&15, row=(lane>>4)*4+reg
#pragma unroll
    for (int mf = 0; mf < 4; mf++)
#pragma unroll
        for (int nf = 0; nf < 8; nf++) {
            int col = col0 + nf * 16 + (lane & 15);
#pragma unroll
            for (int rg = 0; rg < 4; rg++) {
                float v = acc[mf][nf][rg];
                v = v >= 0.f ? v : 0.5f * v;   // leaky relu slope 0.5
                v = v * v;                     // square
                h[(size_t)(m_base + row0 + mf * 16 + rg) * NDIM + col] = f2bf(v);
            }
        }
}

// --- proj GEMM: BM=128 BN=256 BK=64, split-K=2, m97 structure, XOR swizzle.
// Writes BF16 partials BY SLOT: P[split][slot][col] (P = dead W_fc, 21 MiB).
__global__ __launch_bounds__(256, 3) void proj_k(const ushort* __restrict__ h,
                                                 const ushort* __restrict__ Wpj,
                                                 ushort* __restrict__ Part,
                                                 const int* __restrict__ counts,
                                                 const int* __restrict__ offsets)
{
    __shared__ __align__(16) ushort As[128 * 64];
    __shared__ __align__(16) ushort Bs[256 * 64];
    constexpr int KDIM = 4096;
    constexpr int NDIM = 1024;
    constexpr int KSUB = 2048;
    int b = blockIdx.x;                 // 320: 4 n-panels x 2 splits x 40 m
    int nb = (b & 7) >> 1;
    int split = b & 1;
    int ms = b >> 3;
    int e = -1, mt = 0, acct = 0;
#pragma unroll
    for (int i = 0; i < 8; i++) {
        int tiles = (counts[i] + 127) >> 7;
        if (e < 0 && ms < acct + tiles) { e = i; mt = ms - acct; }
        acct += tiles;
    }
    if (e < 0) return;
    int m_base = offsets[e] + mt * 128;
    int n_base = nb * 256;
    int tid = threadIdx.x, w = tid >> 6, lane = tid & 63;
    int wm = w >> 1, wn = w & 1;
    int lr = lane >> 3;
    int lcs = (((lane & 7) ^ lr) << 3);
    int kbase = split * KSUB;
    const ushort* Bb = Wpj + (size_t)e * NDIM * KDIM + (size_t)n_base * KDIM + kbase;
    const ushort* arow[4];
#pragma unroll
    for (int i = 0; i < 4; i++)
        arow[i] = h + (size_t)(m_base + i * 32 + w * 8 + lr) * KDIM + kbase + lcs;
    f32x4 acc[4][8];
#pragma unroll
    for (int i = 0; i < 4; i++)
#pragma unroll
        for (int j = 0; j < 8; j++) acc[i][j] = (f32x4){0.f, 0.f, 0.f, 0.f};

    for (int t = 0; t < KSUB / 64; t++) {
        int k0 = t * 64;
#pragma unroll
        for (int i = 0; i < 4; i++)
            gload_lds16(arow[i] + k0, &As[(i * 32 + w * 8) * 64]);
#pragma unroll
        for (int i = 0; i < 8; i++) {
            int r0 = i * 32 + w * 8;
            gload_lds16(Bb + (size_t)(r0 + lr) * KDIM + k0 + lcs, &Bs[r0 * 64]);
        }
        __syncthreads();
#pragma unroll
        for (int ks = 0; ks < 2; ks++) {
            short8 a[4], bfr[8];
            int ca = (((ks * 4 + (lane >> 4)) ^ (lane & 7)) << 3);
#pragma unroll
            for (int f = 0; f < 4; f++)
                a[f] = *(const short8*)&As[(wm * 64 + f * 16 + (lane & 15)) * 64 + ca];
#pragma unroll
            for (int f = 0; f < 8; f++)
                bfr[f] = *(const short8*)&Bs[(wn * 128 + f * 16 + (lane & 15)) * 64 + ca];
#pragma unroll
            for (int mf = 0; mf < 4; mf++)
#pragma unroll
                for (int nf = 0; nf < 8; nf++)
                    acc[mf][nf] = __builtin_amdgcn_mfma_f32_16x16x32_bf16(a[mf], bfr[nf], acc[mf][nf], 0, 0, 0);
        }
        __syncthreads();
    }

    ushort* P = Part + (size_t)split * SLOTS * NDIM;
    int col0 = n_base + wn * 128;
    int row0 = wm * 64 + (lane >> 4) * 4;
#pragma unroll
    for (int mf = 0; mf < 4; mf++)
#pragma unroll
        for (int nf = 0; nf < 8; nf++) {
            int col = col0 + nf * 16 + (lane & 15);
#pragma unroll
            for (int rg = 0; rg < 4; rg++)
                P[(size_t)(m_base + row0 + mf * 16 + rg) * NDIM + col] = f2bf(acc[mf][nf][rg]);
        }
}

// -------- reduce: out[tok[slot]] = f32(P0[slot]) + f32(P1[slot]) -------------
__global__ __launch_bounds__(256) void reduce_k(const ushort* __restrict__ P,
                                                const int* __restrict__ tok,
                                                float* __restrict__ out)
{
    int slot = blockIdx.x;
    int t = tok[slot];
    if (t < 0) return;
    int i = threadIdx.x;
    const ushort4* p0 = (const ushort4*)(P + (size_t)slot * DIM);
    const ushort4* p1 = (const ushort4*)(P + (size_t)(SLOTS + slot) * DIM);
    ushort4 a = p0[i], b = p1[i];
    float4* o = (float4*)(out + (size_t)t * DIM);
    o[i] = (float4){bf2f(a.x) + bf2f(b.x), bf2f(a.y) + bf2f(b.y),
                    bf2f(a.z) + bf2f(b.z), bf2f(a.w) + bf2f(b.w)};
}

extern "C" void kernel_launch(void* const* d_in, const int* in_sizes, int n_in,
                              void* d_out, int out_size, void* d_ws, size_t ws_size,
                              hipStream_t stream)
{
    const float* x    = (const float*)d_in[0];
    const float* wr   = (const float*)d_in[1];
    const float* A_fc = (const float*)d_in[2];
    const float* S_fc = (const float*)d_in[3];
    const float* A_pj = (const float*)d_in[4];
    const float* S_pj = (const float*)d_in[5];
    float* out = (float*)d_out;
    char* ws = (char*)d_ws;

    ushort* Wfc   = (ushort*)(ws + OFF_WFC);
    ushort* Part  = (ushort*)(ws + OFF_WFC);   // aliases W_fc (dead after mid_k)
    ushort* Wpj   = (ushort*)(ws + OFF_WPROJ);
    ushort* xb    = (ushort*)(ws + OFF_XB);
    ushort* h     = (ushort*)(ws + OFF_H);
    double* bsum  = (double*)(ws + OFF_BSUM);
    int*    eidx  = (int*)(ws + OFF_EIDX);
    int*    tok   = (int*)(ws + OFF_TOK);
    int*    counts  = (int*)(ws + OFF_CNT);
    int*    offsets = counts + 16;

    front_k<<<T_TOK / 4, 256, 0, stream>>>(x, wr, bsum, eidx, xb);
    plan_k<<<1 + 8192, 256, 0, stream>>>(bsum, eidx, counts, offsets, tok,
                                         out + (size_t)T_TOK * DIM,
                                         A_fc, S_fc, Wfc);
    mid_k<<<640 + 2048, 256, 0, stream>>>(xb, Wfc, h, counts, offsets, tok,
                                          A_pj, S_pj, Wpj);
    // proj: 40 m-tiles x 4 n-panels x split-K=2 -> 320 blocks, bf16 partials
    proj_k<<<320, 256, 0, stream>>>(h, Wpj, Part, counts, offsets);
    reduce_k<<<SLOTS, 256, 0, stream>>>(Part, tok, out);
}

// Round 19
// 164.976 us; speedup vs baseline: 1.9017x; 1.9017x over previous
//
#include <hip/hip_runtime.h>
#include <hip/hip_bf16.h>

// MoE PHM MLP, MI355X. B=2,S=2048,D=1024 -> T=4096 tokens; E=8, N=4, HID=4096.
// Launch chain (r15/r17-proven best, 165.1/165.3 us; r18's (256,3) bound cut
// VGPR 108->84 and 2.4x'd the GEMM inner loop -- reverted to (256,2)):
//   front_k : router (f64 logits/argmax, f32 softmax, bf16 x-copy, prob sums)
//   plan_k  : block 0 = histogram/stable-rank/offsets/aux; blocks 1..8192 =
//             W_fc materialization (overlaps plan)
//   mid_k   : fc GEMM (128x256, indirect A via tok[], leaky(0.5)^2 -> h bf16)
//             + W_proj materialization
//   proj_k  : proj GEMM (128x256, split-K=2) -> BF16 partials BY SLOT
//   reduce_k: out[tok[slot]] = f32(P0[slot]) + f32(P1[slot])
// GEMMs: m97 2-barrier single-buffer structure, XOR-swizzled LDS via
// pre-swizzled global source (measured 0 bank conflicts), XCD-aware decode.

#define T_TOK 4096
#define DIM   1024
#define NEXP  8
#define HIDD  4096
#define SLOTS 5120

static constexpr size_t OFF_WFC   = 0;
static constexpr size_t OFF_WPROJ = 67108864ull;
static constexpr size_t OFF_XB    = 134217728ull;
static constexpr size_t OFF_H     = 144703488ull;
static constexpr size_t OFF_BSUM  = 186646528ull;                     // 64 KB
static constexpr size_t OFF_EIDX  = OFF_BSUM + 1024*8*8;
static constexpr size_t OFF_TOK   = OFF_EIDX + (size_t)T_TOK*4;
static constexpr size_t OFF_CNT   = OFF_TOK + (size_t)SLOTS*4;

typedef __attribute__((ext_vector_type(8))) short short8;
typedef __attribute__((ext_vector_type(4))) float f32x4;

static __device__ __forceinline__ ushort f2bf(float f) {
    __hip_bfloat16 h = __float2bfloat16(f);
    return __builtin_bit_cast(ushort, h);
}

static __device__ __forceinline__ float bf2f(ushort u) {
    return __builtin_bit_cast(float, (unsigned)u << 16);
}

static __device__ __forceinline__ ushort4 f4bf(float4 v) {
    ushort4 b;
    b.x = f2bf(v.x); b.y = f2bf(v.y); b.z = f2bf(v.z); b.w = f2bf(v.w);
    return b;
}

static __device__ __forceinline__ void gload_lds16(const ushort* g, ushort* l) {
    __builtin_amdgcn_global_load_lds((const __attribute__((address_space(1))) void*)g,
                                     (__attribute__((address_space(3))) void*)l,
                                     16, 0, 0);
}

// ---- front: router (f64 logits, argmax, bf16 x copy, per-block prob sums) ---
__global__ __launch_bounds__(256) void front_k(const float* __restrict__ x,
                                               const float* __restrict__ wr,
                                               double* __restrict__ bsum,
                                               int* __restrict__ eidx,
                                               ushort* __restrict__ xb)
{
    __shared__ double shp[4][8];
    int tid = threadIdx.x;
    int w = tid >> 6, lane = tid & 63;
    int t = blockIdx.x * 4 + w;
    const float4* xr = (const float4*)(x + (size_t)t * DIM);
    float4 xv[4];
#pragma unroll
    for (int q = 0; q < 4; q++) xv[q] = xr[q * 64 + lane];
    ushort4* xo = (ushort4*)(xb + (size_t)t * DIM);
#pragma unroll
    for (int q = 0; q < 4; q++) xo[q * 64 + lane] = f4bf(xv[q]);
    double lg[8];
#pragma unroll
    for (int e = 0; e < 8; e++) {
        const float4* wv = (const float4*)(wr + (size_t)e * DIM);
        double s = 0.0;
#pragma unroll
        for (int q = 0; q < 4; q++) {
            float4 a = xv[q], b = wv[q * 64 + lane];
            s += (double)a.x * b.x + (double)a.y * b.y + (double)a.z * b.z + (double)a.w * b.w;
        }
#pragma unroll
        for (int d = 1; d < 64; d <<= 1) s += __shfl_xor(s, d);
        lg[e] = s;
    }
    double m = lg[0];
#pragma unroll
    for (int e = 1; e < 8; e++) m = lg[e] > m ? lg[e] : m;
    // softmax in f32 (argmax stays on f64 logits; probs only feed aux_loss)
    float ex[8], sum = 0.f;
#pragma unroll
    for (int e = 0; e < 8; e++) { ex[e] = __expf((float)(lg[e] - m)); sum += ex[e]; }
    if (lane < 8) shp[w][lane] = (double)(ex[lane] / sum);
    if (lane == 0) {
        int am = 0; double bv = lg[0];
#pragma unroll
        for (int e = 1; e < 8; e++) if (lg[e] > bv) { bv = lg[e]; am = e; }  // first-max = jnp.argmax
        eidx[t] = am;
    }
    __syncthreads();
    if (tid < 8)
        bsum[(size_t)blockIdx.x * 8 + tid] =
            shp[0][tid] + shp[1][tid] + shp[2][tid] + shp[3][tid];
}

// --- plan: block 0 = histogram/rank/offsets/aux; blocks 1.. = W_fc wmat -----
__global__ __launch_bounds__(256) void plan_k(const double* __restrict__ bsum,
                                              const int* __restrict__ eidx,
                                              int* __restrict__ counts,
                                              int* __restrict__ offsets,
                                              int* __restrict__ tok,
                                              float* __restrict__ auxout,
                                              const float* __restrict__ Afc,
                                              const float* __restrict__ Sfc,
                                              ushort* __restrict__ Wfc)
{
    __shared__ int hist[256][8];
    __shared__ double red[256][8];
    __shared__ int offs[8];
    __shared__ float Ash[64];
    int tid = threadIdx.x;
    if (blockIdx.x > 0) {
        // -- W_fc: W[e][j*1024+o][k*256+l] = sum_i A[i,j,k]S[i,o,l], ushort4 --
        int b2 = blockIdx.x - 1;
        int e = b2 >> 10, o = b2 & 1023;
        if (tid < 64) Ash[tid] = Afc[e * 64 + tid];
        __syncthreads();
        int k = tid >> 6, lq = tid & 63;           // k slice, l/4 index
        float4 sv[4];
#pragma unroll
        for (int i = 0; i < 4; i++)
            sv[i] = *(const float4*)&Sfc[((size_t)(e * 4 + i) * 1024 + o) * 256 + lq * 4];
        size_t base = (size_t)e * 4194304ull;
#pragma unroll
        for (int j = 0; j < 4; j++) {
            float a0 = Ash[j * 4 + k], a1 = Ash[16 + j * 4 + k];
            float a2 = Ash[32 + j * 4 + k], a3 = Ash[48 + j * 4 + k];
            float4 v;
            v.x = a0 * sv[0].x + a1 * sv[1].x + a2 * sv[2].x + a3 * sv[3].x;
            v.y = a0 * sv[0].y + a1 * sv[1].y + a2 * sv[2].y + a3 * sv[3].y;
            v.z = a0 * sv[0].z + a1 * sv[1].z + a2 * sv[2].z + a3 * sv[3].z;
            v.w = a0 * sv[0].w + a1 * sv[1].w + a2 * sv[2].w + a3 * sv[3].w;
            *(ushort4*)&Wfc[base + (size_t)(j * 1024 + o) * 1024 + k * 256 + lq * 4] = f4bf(v);
        }
        return;
    }
    // ------------------------------ plan (block 0) --------------------------
    for (int i = tid; i < SLOTS; i += 256) tok[i] = -1;
    int base = tid * 16;
    int le[16];
    int lc[8] = {0,0,0,0,0,0,0,0};
#pragma unroll
    for (int j = 0; j < 16; j++) { le[j] = eidx[base + j]; lc[le[j]]++; }
#pragma unroll
    for (int e = 0; e < 8; e++) hist[tid][e] = lc[e];
    __syncthreads();
    for (int s = 1; s < 256; s <<= 1) {
        int v[8];
        if (tid >= s) {
#pragma unroll
            for (int e = 0; e < 8; e++) v[e] = hist[tid - s][e];
        }
        __syncthreads();
        if (tid >= s) {
#pragma unroll
            for (int e = 0; e < 8; e++) hist[tid][e] += v[e];
        }
        __syncthreads();
    }
    int myBase[8];
#pragma unroll
    for (int e = 0; e < 8; e++) myBase[e] = hist[tid][e] - lc[e];
    if (tid == 0) {
        int off = 0;
#pragma unroll
        for (int e = 0; e < 8; e++) {
            int c = hist[255][e];
            counts[e] = c;
            offsets[e] = off; offs[e] = off;
            off += (c + 127) & ~127;
        }
    }
    __syncthreads();
    int cur[8];
#pragma unroll
    for (int e = 0; e < 8; e++) cur[e] = myBase[e];
#pragma unroll
    for (int j = 0; j < 16; j++) {
        int e = le[j];
        tok[offs[e] + cur[e]++] = base + j;
    }
    double ps[8] = {0, 0, 0, 0, 0, 0, 0, 0};
    for (int b = tid; b < 1024; b += 256) {
#pragma unroll
        for (int e = 0; e < 8; e++) ps[e] += bsum[(size_t)b * 8 + e];
    }
#pragma unroll
    for (int e = 0; e < 8; e++) red[tid][e] = ps[e];
    __syncthreads();
    for (int s = 128; s > 0; s >>= 1) {
        if (tid < s) {
#pragma unroll
            for (int e = 0; e < 8; e++) red[tid][e] += red[tid + s][e];
        }
        __syncthreads();
    }
    if (tid == 0) {
        double aux = 0.0;
#pragma unroll
        for (int e = 0; e < 8; e++)
            aux += ((double)hist[255][e] / T_TOK) * (red[0][e] / T_TOK);
        auxout[0] = (float)(aux * NEXP);
    }
}

// ---- mid: blocks [0,640) = fc GEMM, [640,2688) = W_proj materialization ----
__global__ __launch_bounds__(256, 2) void mid_k(const ushort* __restrict__ xb,
                                                const ushort* __restrict__ Wfc,
                                                ushort* __restrict__ h,
                                                const int* __restrict__ counts,
                                                const int* __restrict__ offsets,
                                                const int* __restrict__ tok,
                                                const float* __restrict__ Apj,
                                                const float* __restrict__ Spj,
                                                ushort* __restrict__ Wpj)
{
    __shared__ __align__(16) ushort As[128 * 64];
    __shared__ __align__(16) ushort Bs[256 * 64];
    __shared__ float Ashf[64];
    int b = blockIdx.x;
    int tid = threadIdx.x;
    if (b >= 640) {
        // W_proj: W[e][j*256+o][k*1024+l] = sum_i A[i,j,k]S[i,o,l], ushort4 ---
        int b2 = b - 640;
        int e = b2 >> 8, o = b2 & 255;
        if (tid < 64) Ashf[tid] = Apj[e * 64 + tid];
        __syncthreads();
        float4 sv[4];
#pragma unroll
        for (int i = 0; i < 4; i++)
            sv[i] = *(const float4*)&Spj[((size_t)(e * 4 + i) * 256 + o) * 1024 + tid * 4];
        size_t base = (size_t)e * 4194304ull;
#pragma unroll
        for (int j = 0; j < 4; j++)
#pragma unroll
            for (int k = 0; k < 4; k++) {
                float a0 = Ashf[j * 4 + k], a1 = Ashf[16 + j * 4 + k];
                float a2 = Ashf[32 + j * 4 + k], a3 = Ashf[48 + j * 4 + k];
                float4 v;
                v.x = a0 * sv[0].x + a1 * sv[1].x + a2 * sv[2].x + a3 * sv[3].x;
                v.y = a0 * sv[0].y + a1 * sv[1].y + a2 * sv[2].y + a3 * sv[3].y;
                v.z = a0 * sv[0].z + a1 * sv[1].z + a2 * sv[2].z + a3 * sv[3].z;
                v.w = a0 * sv[0].w + a1 * sv[1].w + a2 * sv[2].w + a3 * sv[3].w;
                *(ushort4*)&Wpj[base + (size_t)(j * 256 + o) * 4096 + k * 1024 + tid * 4] = f4bf(v);
            }
        return;
    }
    // ------------------------------ fc GEMM ---------------------------------
    constexpr int KDIM = 1024;
    constexpr int NDIM = 4096;
    int r = b >> 3;
    int nb = (b & 7) * 2 + r / 40;     // 16 n-panels, 2 per XCD
    int ms = r % 40;
    int e = -1, mt = 0, acct = 0;
#pragma unroll
    for (int i = 0; i < 8; i++) {
        int tiles = (counts[i] + 127) >> 7;
        if (e < 0 && ms < acct + tiles) { e = i; mt = ms - acct; }
        acct += tiles;
    }
    if (e < 0) return;
    int m_base = offsets[e] + mt * 128;
    int n_base = nb * 256;
    int w = tid >> 6, lane = tid & 63;
    int wm = w >> 1, wn = w & 1;
    const ushort* Bb = Wfc + (size_t)e * NDIM * KDIM + (size_t)n_base * KDIM;
    int lr = lane >> 3;                        // staging row within 8-row group
    int lcs = (((lane & 7) ^ lr) << 3);        // swizzled source chunk (ushorts)
    const ushort* arow[4];
#pragma unroll
    for (int i = 0; i < 4; i++) {
        int sl = m_base + i * 32 + w * 8 + lr;
        int rt = tok[sl]; if (rt < 0) rt = 0;
        arow[i] = xb + (size_t)rt * KDIM + lcs;
    }
    f32x4 acc[4][8];
#pragma unroll
    for (int i = 0; i < 4; i++)
#pragma unroll
        for (int j = 0; j < 8; j++) acc[i][j] = (f32x4){0.f, 0.f, 0.f, 0.f};

    for (int t = 0; t < KDIM / 64; t++) {
        int k0 = t * 64;
#pragma unroll
        for (int i = 0; i < 4; i++)
            gload_lds16(arow[i] + k0, &As[(i * 32 + w * 8) * 64]);
#pragma unroll
        for (int i = 0; i < 8; i++) {
            int r0 = i * 32 + w * 8;
            gload_lds16(Bb + (size_t)(r0 + lr) * KDIM + k0 + lcs, &Bs[r0 * 64]);
        }
        __syncthreads();
#pragma unroll
        for (int ks = 0; ks < 2; ks++) {
            short8 a[4], bfr[8];
            int ca = (((ks * 4 + (lane >> 4)) ^ (lane & 7)) << 3);
#pragma unroll
            for (int f = 0; f < 4; f++)
                a[f] = *(const short8*)&As[(wm * 64 + f * 16 + (lane & 15)) * 64 + ca];
#pragma unroll
            for (int f = 0; f < 8; f++)
                bfr[f] = *(const short8*)&Bs[(wn * 128 + f * 16 + (lane & 15)) * 64 + ca];
#pragma unroll
            for (int mf = 0; mf < 4; mf++)
#pragma unroll
                for (int nf = 0; nf < 8; nf++)
                    acc[mf][nf] = __builtin_amdgcn_mfma_f32_16x16x32_bf16(a[mf], bfr[nf], acc[mf][nf], 0, 0, 0);
        }
        __syncthreads();
    }

    int col0 = n_base + wn * 128;
    int row0 = wm * 64 + (lane >> 4) * 4;   // C/D: col=lane&15, row=(lane>>4)*4+reg
#pragma unroll
    for (int mf = 0; mf < 4; mf++)
#pragma unroll
        for (int nf = 0; nf < 8; nf++) {
            int col = col0 + nf * 16 + (lane & 15);
#pragma unroll
            for (int rg = 0; rg < 4; rg++) {
                float v = acc[mf][nf][rg];
                v = v >= 0.f ? v : 0.5f * v;   // leaky relu slope 0.5
                v = v * v;                     // square
                h[(size_t)(m_base + row0 + mf * 16 + rg) * NDIM + col] = f2bf(v);
            }
        }
}

// --- proj GEMM: BM=128 BN=256 BK=64, split-K=2, m97 structure, XOR swizzle.
// Writes BF16 partials BY SLOT: P[split][slot][col] (P = dead W_fc, 21 MiB).
__global__ __launch_bounds__(256, 2) void proj_k(const ushort* __restrict__ h,
                                                 const ushort* __restrict__ Wpj,
                                                 ushort* __restrict__ Part,
                                                 const int* __restrict__ counts,
                                                 const int* __restrict__ offsets)
{
    __shared__ __align__(16) ushort As[128 * 64];
    __shared__ __align__(16) ushort Bs[256 * 64];
    constexpr int KDIM = 4096;
    constexpr int NDIM = 1024;
    constexpr int KSUB = 2048;
    int b = blockIdx.x;                 // 320: 4 n-panels x 2 splits x 40 m
    int nb = (b & 7) >> 1;
    int split = b & 1;
    int ms = b >> 3;
    int e = -1, mt = 0, acct = 0;
#pragma unroll
    for (int i = 0; i < 8; i++) {
        int tiles = (counts[i] + 127) >> 7;
        if (e < 0 && ms < acct + tiles) { e = i; mt = ms - acct; }
        acct += tiles;
    }
    if (e < 0) return;
    int m_base = offsets[e] + mt * 128;
    int n_base = nb * 256;
    int tid = threadIdx.x, w = tid >> 6, lane = tid & 63;
    int wm = w >> 1, wn = w & 1;
    int lr = lane >> 3;
    int lcs = (((lane & 7) ^ lr) << 3);
    int kbase = split * KSUB;
    const ushort* Bb = Wpj + (size_t)e * NDIM * KDIM + (size_t)n_base * KDIM + kbase;
    const ushort* arow[4];
#pragma unroll
    for (int i = 0; i < 4; i++)
        arow[i] = h + (size_t)(m_base + i * 32 + w * 8 + lr) * KDIM + kbase + lcs;
    f32x4 acc[4][8];
#pragma unroll
    for (int i = 0; i < 4; i++)
#pragma unroll
        for (int j = 0; j < 8; j++) acc[i][j] = (f32x4){0.f, 0.f, 0.f, 0.f};

    for (int t = 0; t < KSUB / 64; t++) {
        int k0 = t * 64;
#pragma unroll
        for (int i = 0; i < 4; i++)
            gload_lds16(arow[i] + k0, &As[(i * 32 + w * 8) * 64]);
#pragma unroll
        for (int i = 0; i < 8; i++) {
            int r0 = i * 32 + w * 8;
            gload_lds16(Bb + (size_t)(r0 + lr) * KDIM + k0 + lcs, &Bs[r0 * 64]);
        }
        __syncthreads();
#pragma unroll
        for (int ks = 0; ks < 2; ks++) {
            short8 a[4], bfr[8];
            int ca = (((ks * 4 + (lane >> 4)) ^ (lane & 7)) << 3);
#pragma unroll
            for (int f = 0; f < 4; f++)
                a[f] = *(const short8*)&As[(wm * 64 + f * 16 + (lane & 15)) * 64 + ca];
#pragma unroll
            for (int f = 0; f < 8; f++)
                bfr[f] = *(const short8*)&Bs[(wn * 128 + f * 16 + (lane & 15)) * 64 + ca];
#pragma unroll
            for (int mf = 0; mf < 4; mf++)
#pragma unroll
                for (int nf = 0; nf < 8; nf++)
                    acc[mf][nf] = __builtin_amdgcn_mfma_f32_16x16x32_bf16(a[mf], bfr[nf], acc[mf][nf], 0, 0, 0);
        }
        __syncthreads();
    }

    ushort* P = Part + (size_t)split * SLOTS * NDIM;
    int col0 = n_base + wn * 128;
    int row0 = wm * 64 + (lane >> 4) * 4;
#pragma unroll
    for (int mf = 0; mf < 4; mf++)
#pragma unroll
        for (int nf = 0; nf < 8; nf++) {
            int col = col0 + nf * 16 + (lane & 15);
#pragma unroll
            for (int rg = 0; rg < 4; rg++)
                P[(size_t)(m_base + row0 + mf * 16 + rg) * NDIM + col] = f2bf(acc[mf][nf][rg]);
        }
}

// -------- reduce: out[tok[slot]] = f32(P0[slot]) + f32(P1[slot]) -------------
__global__ __launch_bounds__(256) void reduce_k(const ushort* __restrict__ P,
                                                const int* __restrict__ tok,
                                                float* __restrict__ out)
{
    int slot = blockIdx.x;
    int t = tok[slot];
    if (t < 0) return;
    int i = threadIdx.x;
    const ushort4* p0 = (const ushort4*)(P + (size_t)slot * DIM);
    const ushort4* p1 = (const ushort4*)(P + (size_t)(SLOTS + slot) * DIM);
    ushort4 a = p0[i], b = p1[i];
    float4* o = (float4*)(out + (size_t)t * DIM);
    o[i] = (float4){bf2f(a.x) + bf2f(b.x), bf2f(a.y) + bf2f(b.y),
                    bf2f(a.z) + bf2f(b.z), bf2f(a.w) + bf2f(b.w)};
}

extern "C" void kernel_launch(void* const* d_in, const int* in_sizes, int n_in,
                              void* d_out, int out_size, void* d_ws, size_t ws_size,
                              hipStream_t stream)
{
    const float* x    = (const float*)d_in[0];
    const float* wr   = (const float*)d_in[1];
    const float* A_fc = (const float*)d_in[2];
    const float* S_fc = (const float*)d_in[3];
    const float* A_pj = (const float*)d_in[4];
    const float* S_pj = (const float*)d_in[5];
    float* out = (float*)d_out;
    char* ws = (char*)d_ws;

    ushort* Wfc   = (ushort*)(ws + OFF_WFC);
    ushort* Part  = (ushort*)(ws + OFF_WFC);   // aliases W_fc (dead after mid_k)
    ushort* Wpj   = (ushort*)(ws + OFF_WPROJ);
    ushort* xb    = (ushort*)(ws + OFF_XB);
    ushort* h     = (ushort*)(ws + OFF_H);
    double* bsum  = (double*)(ws + OFF_BSUM);
    int*    eidx  = (int*)(ws + OFF_EIDX);
    int*    tok   = (int*)(ws + OFF_TOK);
    int*    counts  = (int*)(ws + OFF_CNT);
    int*    offsets = counts + 16;

    front_k<<<T_TOK / 4, 256, 0, stream>>>(x, wr, bsum, eidx, xb);
    plan_k<<<1 + 8192, 256, 0, stream>>>(bsum, eidx, counts, offsets, tok,
                                         out + (size_t)T_TOK * DIM,
                                         A_fc, S_fc, Wfc);
    mid_k<<<640 + 2048, 256, 0, stream>>>(xb, Wfc, h, counts, offsets, tok,
                                          A_pj, S_pj, Wpj);
    // proj: 40 m-tiles x 4 n-panels x split-K=2 -> 320 blocks, bf16 partials
    proj_k<<<320, 256, 0, stream>>>(h, Wpj, Part, counts, offsets);
    reduce_k<<<SLOTS, 256, 0, stream>>>(Part, tok, out);
}